// Round 1
// baseline (92.095 us; speedup 1.0000x reference)
//
#include <hip/hip_runtime.h>
#include <math.h>

#define NUM_GRAPHS 16
#define PI_F 3.14159265358979323846f
#define INV_SQRT_2PI 0.3989422804014327f

// Kernel A: node segment boundaries (batch is sorted) + out init with -0.5*self_energy
__global__ void gto_init_kernel(const float* __restrict__ q,
                                const int* __restrict__ batch, int n_nodes,
                                float* __restrict__ out,
                                int* __restrict__ node_start /* NUM_GRAPHS+1 */) {
    __shared__ float acc[NUM_GRAPHS];
    int t = threadIdx.x;
    if (t < NUM_GRAPHS) acc[t] = 0.f;
    __syncthreads();

    // lower_bound(batch, g) for g = 0..NUM_GRAPHS
    if (t <= NUM_GRAPHS) {
        int lo = 0, hi = n_nodes;
        while (lo < hi) {
            int mid = (lo + hi) >> 1;
            if (batch[mid] < t) lo = mid + 1; else hi = mid;
        }
        node_start[t] = lo;
    }

    // self-energy: sum q^2 per graph
    for (int i = t; i < n_nodes; i += blockDim.x) {
        float qi = q[i];
        atomicAdd(&acc[batch[i]], qi * qi);
    }
    __syncthreads();
    if (t < NUM_GRAPHS) {
        out[t] = -0.5f * acc[t] * INV_SQRT_2PI;
    }
}

#define WAVES_PER_BLOCK 4
#define K_PER_WAVE 8
#define K_PER_BLOCK (WAVES_PER_BLOCK * K_PER_WAVE)

// Kernel B: per-k structure factors + energy accumulation
__global__ void __launch_bounds__(256)
gto_energy_kernel(const float* __restrict__ kvec,   // [K,3]
                  const float* __restrict__ knorm2, // [K]
                  const int*   __restrict__ kbatch, // [K] sorted
                  const float* __restrict__ k0mask, // [K]
                  const float* __restrict__ q,      // [N]
                  const float* __restrict__ pos,    // [N,3]
                  const float* __restrict__ volume, // [B]
                  const int*   __restrict__ node_start, // [B+1]
                  float* __restrict__ out, int K) {
    __shared__ float gacc[NUM_GRAPHS];
    int t = threadIdx.x;
    if (t < NUM_GRAPHS) gacc[t] = 0.f;
    __syncthreads();

    int wave = t >> 6;
    int lane = t & 63;
    int kbase = (blockIdx.x * WAVES_PER_BLOCK + wave) * K_PER_WAVE;

    for (int kk = 0; kk < K_PER_WAVE; ++kk) {
        int k = kbase + kk;
        if (k >= K) break;
        int g = kbatch[k];
        float kx = kvec[3 * k + 0];
        float ky = kvec[3 * k + 1];
        float kz = kvec[3 * k + 2];
        int s = node_start[g];
        int e = node_start[g + 1];

        float C = 0.f, S = 0.f;
        for (int j = s + lane; j < e; j += 64) {
            float px = pos[3 * j + 0];
            float py = pos[3 * j + 1];
            float pz = pos[3 * j + 2];
            float inner = fmaf(kx, px, fmaf(ky, py, kz * pz));
            float sv, cv;
            __sincosf(inner, &sv, &cv);
            float qj = q[j];
            C = fmaf(cv, qj, C);
            S = fmaf(sv, qj, S);
        }
        // 64-lane butterfly reduce
        #pragma unroll
        for (int off = 32; off > 0; off >>= 1) {
            C += __shfl_xor(C, off, 64);
            S += __shfl_xor(S, off, 64);
        }
        if (lane == 0) {
            float kn2 = knorm2[k];
            float fs = __expf(-0.5f * kn2);          // sigma = 1
            float kfac = (k0mask[k] > 0.f) ? 0.f : 1.f / kn2;
            float e_k = 4.f * PI_F * kfac * fs * fs * (C * C + S * S) / volume[g];
            atomicAdd(&gacc[g], e_k);
        }
    }
    __syncthreads();
    if (t < NUM_GRAPHS && gacc[t] != 0.f) {
        atomicAdd(&out[t], gacc[t]);
    }
}

extern "C" void kernel_launch(void* const* d_in, const int* in_sizes, int n_in,
                              void* d_out, int out_size, void* d_ws, size_t ws_size,
                              hipStream_t stream) {
    const float* k_vectors  = (const float*)d_in[0];  // [K,3]
    const float* k_norm2    = (const float*)d_in[1];  // [K]
    const int*   k_batch    = (const int*)  d_in[2];  // [K]
    const float* k0_mask    = (const float*)d_in[3];  // [K]
    const float* src_feats  = (const float*)d_in[4];  // [N,1]
    const float* positions  = (const float*)d_in[5];  // [N,3]
    const int*   batch      = (const int*)  d_in[6];  // [N]
    const float* volume     = (const float*)d_in[7];  // [B]
    // d_in[8] = pbc (bool [B,3]) — unused by the math

    int K = in_sizes[1];
    int N = in_sizes[4];
    float* out = (float*)d_out;
    int* node_start = (int*)d_ws;  // NUM_GRAPHS+1 ints

    gto_init_kernel<<<1, 256, 0, stream>>>(src_feats, batch, N, out, node_start);

    int blocks = (K + K_PER_BLOCK - 1) / K_PER_BLOCK;
    gto_energy_kernel<<<blocks, 256, 0, stream>>>(
        k_vectors, k_norm2, k_batch, k0_mask, src_feats, positions,
        volume, node_start, out, K);
}